// Round 1
// baseline (434.589 us; speedup 1.0000x reference)
//
#include <hip/hip_runtime.h>
#include <stdint.h>

#define N_TOTAL   33554432u          // 8*1*64*256*256, also == norm_term = 2^25
#define N_VEC4    (N_TOTAL / 4u)     // 8,388,608 float4 per array
#define K_SEL     262144u            // MIN_KEPT
#define NBIN1     4096
#define NBIN3     256

// ws layout (bytes)
#define OFF_HSAMP 0
#define OFF_H1C   16384
#define OFF_H1S   32768
#define OFF_H2C   49152
#define OFF_H2S   65536
#define OFF_H3C   81920
#define OFF_H3S   (81920 + 1024)
#define OFF_CTRL  (81920 + 2048)
#define META_BYTES 98304             // 96 KiB, zeroed each call

struct Ctrl {
    unsigned tlo;          // pre-threshold bit pattern (bucket edge)
    unsigned cand_count;   // number of compacted candidates
    unsigned b1; unsigned r1; float S1;
    unsigned b2; unsigned r2; float S2;
};

__device__ __forceinline__ float loss_of(float p, float t, float w) {
    float d = p - t;
    return w * (d * d) * 0x1p-25f;   // exact /2^25, matches w*(p-t)^2/norm bitwise
}

// ---------------- sampling: 512 chunks of 1024 elems, every 65536 elems ----
__global__ __launch_bounds__(256) void k_sample(const float4* __restrict__ p,
                                                const float4* __restrict__ t,
                                                const float4* __restrict__ w,
                                                unsigned* __restrict__ hist) {
    __shared__ unsigned hc[NBIN1];
    for (int j = threadIdx.x; j < NBIN1; j += 256) hc[j] = 0;
    __syncthreads();
    // block b handles chunks [b*8, b*8+8); chunk c = 256 float4 at base c*16384
    for (int c = blockIdx.x * 8; c < blockIdx.x * 8 + 8; ++c) {
        int i = c * 16384 + (int)threadIdx.x;
        float4 pv = p[i], tv = t[i], wv = w[i];
        unsigned b0 = __float_as_uint(loss_of(pv.x, tv.x, wv.x)) >> 20;
        unsigned b1 = __float_as_uint(loss_of(pv.y, tv.y, wv.y)) >> 20;
        unsigned b2 = __float_as_uint(loss_of(pv.z, tv.z, wv.z)) >> 20;
        unsigned b3 = __float_as_uint(loss_of(pv.w, tv.w, wv.w)) >> 20;
        atomicAdd(&hc[b0], 1u); atomicAdd(&hc[b1], 1u);
        atomicAdd(&hc[b2], 1u); atomicAdd(&hc[b3], 1u);
    }
    __syncthreads();
    for (int j = threadIdx.x; j < NBIN1; j += 256) {
        unsigned v = hc[j];
        if (v) atomicAdd(&hist[j], v);
    }
}

__global__ __launch_bounds__(256) void k_scan_sample(const unsigned* __restrict__ hist,
                                                     Ctrl* __restrict__ c, unsigned CAP) {
    __shared__ unsigned seg[256];
    unsigned t = threadIdx.x;
    unsigned s = 0;
    for (int j = 0; j < 16; ++j) s += hist[t * 16 + j];
    seg[t] = s;
    __syncthreads();
    if (t == 0) {
        unsigned full_target = 3u * K_SEL;                    // aim: capture ~3k elems
        if (full_target > CAP / 2u) full_target = CAP / 2u;   // keep within buffer
        if (full_target < K_SEL + K_SEL / 8u) full_target = K_SEL + K_SEL / 8u;
        unsigned starget = full_target >> 6;                  // 1/64 sampling
        int margin = (CAP >= 4u * K_SEL) ? 4 : 1;
        unsigned cum = 0;
        int found = 0;
        for (int sg = 255; sg >= 0; --sg) {
            if (cum + seg[sg] >= starget) {
                unsigned c2 = cum;
                found = sg * 16;
                for (int b = sg * 16 + 15; b >= sg * 16; --b) {
                    c2 += hist[b];
                    if (c2 >= starget) { found = b; break; }
                }
                break;
            }
            cum += seg[sg];
        }
        found -= margin;
        if (found < 0) found = 0;
        c->tlo = ((unsigned)found) << 20;
    }
}

// ---------------- main pass: compute loss, compact >= tlo ------------------
__global__ __launch_bounds__(256) void k_compact(const float4* __restrict__ p,
                                                 const float4* __restrict__ t,
                                                 const float4* __restrict__ w,
                                                 float* __restrict__ cand,
                                                 Ctrl* __restrict__ c, unsigned CAP) {
    __shared__ float stage[4096];
    __shared__ unsigned scnt, flushN, gbase;
    if (threadIdx.x == 0) scnt = 0;
    __syncthreads();
    const unsigned tlo = c->tlo;
    const unsigned stride = gridDim.x * 256u;
    // exact division: N_VEC4 / (2048*256) = 16 iterations for every thread
    for (unsigned i = blockIdx.x * 256u + threadIdx.x; i < N_VEC4; i += stride) {
        float4 pv = p[i], tv = t[i], wv = w[i];
        float l0 = loss_of(pv.x, tv.x, wv.x);
        float l1 = loss_of(pv.y, tv.y, wv.y);
        float l2 = loss_of(pv.z, tv.z, wv.z);
        float l3 = loss_of(pv.w, tv.w, wv.w);
        if (__float_as_uint(l0) >= tlo) { unsigned ix = atomicAdd(&scnt, 1u); stage[ix] = l0; }
        if (__float_as_uint(l1) >= tlo) { unsigned ix = atomicAdd(&scnt, 1u); stage[ix] = l1; }
        if (__float_as_uint(l2) >= tlo) { unsigned ix = atomicAdd(&scnt, 1u); stage[ix] = l2; }
        if (__float_as_uint(l3) >= tlo) { unsigned ix = atomicAdd(&scnt, 1u); stage[ix] = l3; }
        __syncthreads();
        if (threadIdx.x == 0) flushN = (scnt >= 3072u) ? scnt : 0u;
        __syncthreads();
        unsigned n = flushN;
        if (n) {
            if (threadIdx.x == 0) gbase = atomicAdd(&c->cand_count, n);
            __syncthreads();
            unsigned gb = gbase;
            for (unsigned j = threadIdx.x; j < n; j += 256u) {
                unsigned pos = gb + j;
                if (pos < CAP) cand[pos] = stage[j];
            }
            __syncthreads();
            if (threadIdx.x == 0) scnt = 0;
            __syncthreads();
        }
    }
    __syncthreads();
    unsigned n = scnt;
    if (n) {
        if (threadIdx.x == 0) gbase = atomicAdd(&c->cand_count, n);
        __syncthreads();
        unsigned gb = gbase;
        for (unsigned j = threadIdx.x; j < n; j += 256u) {
            unsigned pos = gb + j;
            if (pos < CAP) cand[pos] = stage[j];
        }
    }
}

// ---------------- radix-select level 1/2 histograms (4096 bins) ------------
__global__ __launch_bounds__(256) void k_hist1(const float* __restrict__ cand,
                                               const Ctrl* __restrict__ c,
                                               unsigned* __restrict__ hc_g,
                                               float* __restrict__ hs_g, unsigned CAP) {
    __shared__ unsigned hc[NBIN1];
    __shared__ float hs[NBIN1];
    for (int j = threadIdx.x; j < NBIN1; j += 256) { hc[j] = 0; hs[j] = 0.f; }
    __syncthreads();
    unsigned m = c->cand_count; if (m > CAP) m = CAP;
    for (unsigned i = blockIdx.x * 256u + threadIdx.x; i < m; i += gridDim.x * 256u) {
        float v = cand[i];
        unsigned b = __float_as_uint(v) >> 20;
        atomicAdd(&hc[b], 1u);
        atomicAdd(&hs[b], v);
    }
    __syncthreads();
    for (int j = threadIdx.x; j < NBIN1; j += 256) {
        unsigned cv = hc[j];
        if (cv) { atomicAdd(&hc_g[j], cv); atomicAdd(&hs_g[j], hs[j]); }
    }
}

__global__ __launch_bounds__(256) void k_hist2(const float* __restrict__ cand,
                                               const Ctrl* __restrict__ c,
                                               unsigned* __restrict__ hc_g,
                                               float* __restrict__ hs_g, unsigned CAP) {
    __shared__ unsigned hc[NBIN1];
    __shared__ float hs[NBIN1];
    for (int j = threadIdx.x; j < NBIN1; j += 256) { hc[j] = 0; hs[j] = 0.f; }
    __syncthreads();
    unsigned m = c->cand_count; if (m > CAP) m = CAP;
    const unsigned b1 = c->b1;
    for (unsigned i = blockIdx.x * 256u + threadIdx.x; i < m; i += gridDim.x * 256u) {
        float v = cand[i];
        unsigned bits = __float_as_uint(v);
        if ((bits >> 20) == b1) {
            unsigned b = (bits >> 8) & 0xFFFu;
            atomicAdd(&hc[b], 1u);
            atomicAdd(&hs[b], v);
        }
    }
    __syncthreads();
    for (int j = threadIdx.x; j < NBIN1; j += 256) {
        unsigned cv = hc[j];
        if (cv) { atomicAdd(&hc_g[j], cv); atomicAdd(&hs_g[j], hs[j]); }
    }
}

__global__ __launch_bounds__(256) void k_hist3(const float* __restrict__ cand,
                                               const Ctrl* __restrict__ c,
                                               unsigned* __restrict__ hc_g,
                                               float* __restrict__ hs_g, unsigned CAP) {
    __shared__ unsigned hc[NBIN3];
    __shared__ float hs[NBIN3];
    if (threadIdx.x < NBIN3) { hc[threadIdx.x] = 0; hs[threadIdx.x] = 0.f; }
    __syncthreads();
    unsigned m = c->cand_count; if (m > CAP) m = CAP;
    const unsigned key = (c->b1 << 12) | c->b2;   // bits[31:8]
    for (unsigned i = blockIdx.x * 256u + threadIdx.x; i < m; i += gridDim.x * 256u) {
        float v = cand[i];
        unsigned bits = __float_as_uint(v);
        if ((bits >> 8) == key) {
            unsigned b = bits & 0xFFu;
            atomicAdd(&hc[b], 1u);
            atomicAdd(&hs[b], v);
        }
    }
    __syncthreads();
    if (threadIdx.x < NBIN3) {
        unsigned cv = hc[threadIdx.x];
        if (cv) { atomicAdd(&hc_g[threadIdx.x], cv); atomicAdd(&hs_g[threadIdx.x], hs[threadIdx.x]); }
    }
}

// ---------------- 4096-bin scan (level = 1 or 2) ---------------------------
__global__ __launch_bounds__(256) void k_scan4096(const unsigned* __restrict__ hc,
                                                  const float* __restrict__ hs,
                                                  Ctrl* __restrict__ c, int level) {
    __shared__ unsigned seg[256];
    __shared__ float red[256];
    __shared__ unsigned sh_b, sh_r;
    unsigned t = threadIdx.x;
    unsigned target = (level == 1) ? K_SEL : c->r1;
    unsigned s = 0;
    for (int j = 0; j < 16; ++j) s += hc[t * 16 + j];
    seg[t] = s;
    __syncthreads();
    if (t == 0) {
        unsigned cum = 0, bsel = 0, r = target;
        for (int sg = 255; sg >= 0; --sg) {
            if (cum + seg[sg] >= target) {
                for (int b = sg * 16 + 15; ; --b) {
                    unsigned h = hc[b];
                    if (cum + h >= target) { bsel = (unsigned)b; r = target - cum; break; }
                    cum += h;
                }
                break;
            }
            cum += seg[sg];
        }
        sh_b = bsel; sh_r = r;
    }
    __syncthreads();
    unsigned bsel = sh_b;
    float ps = 0.f;
    for (int j = t; j < NBIN1; j += 256)
        if (j > (int)bsel) ps += hs[j];
    red[t] = ps;
    __syncthreads();
    for (int off = 128; off; off >>= 1) {
        if ((int)t < off) red[t] += red[t + off];
        __syncthreads();
    }
    if (t == 0) {
        if (level == 1) { c->b1 = sh_b; c->r1 = sh_r; c->S1 = red[0]; }
        else            { c->b2 = sh_b; c->r2 = sh_r; c->S2 = red[0]; }
    }
}

// ---------------- final 256-bin scan + output ------------------------------
__global__ __launch_bounds__(256) void k_final(const unsigned* __restrict__ hc,
                                               const float* __restrict__ hs,
                                               const Ctrl* __restrict__ c,
                                               float* __restrict__ out) {
    __shared__ unsigned shc[256];
    __shared__ float red[256];
    __shared__ unsigned sh_b, sh_r;
    unsigned t = threadIdx.x;
    shc[t] = hc[t];
    __syncthreads();
    if (t == 0) {
        unsigned target = c->r2;
        unsigned cum = 0, bsel = 0, r = target;
        for (int b = 255; b >= 0; --b) {
            unsigned h = shc[b];
            if (cum + h >= target) { bsel = (unsigned)b; r = target - cum; break; }
            cum += h;
        }
        sh_b = bsel; sh_r = r;
    }
    __syncthreads();
    unsigned bsel = sh_b;
    red[t] = (t > bsel) ? hs[t] : 0.f;
    __syncthreads();
    for (int off = 128; off; off >>= 1) {
        if ((int)t < off) red[t] += red[t + off];
        __syncthreads();
    }
    if (t == 0) {
        unsigned tb = (c->b1 << 20) | (c->b2 << 8) | sh_b;
        float T = __uint_as_float(tb);
        float total = c->S1 + c->S2 + red[0] + (float)sh_r * T;
        out[0] = total / (float)K_SEL;
    }
}

extern "C" void kernel_launch(void* const* d_in, const int* in_sizes, int n_in,
                              void* d_out, int out_size, void* d_ws, size_t ws_size,
                              hipStream_t stream) {
    const float4* p = (const float4*)d_in[0];
    const float4* t = (const float4*)d_in[1];
    const float4* w = (const float4*)d_in[2];
    char* ws = (char*)d_ws;
    unsigned* hsamp = (unsigned*)(ws + OFF_HSAMP);
    unsigned* h1c = (unsigned*)(ws + OFF_H1C);
    float*    h1s = (float*)(ws + OFF_H1S);
    unsigned* h2c = (unsigned*)(ws + OFF_H2C);
    float*    h2s = (float*)(ws + OFF_H2S);
    unsigned* h3c = (unsigned*)(ws + OFF_H3C);
    float*    h3s = (float*)(ws + OFF_H3S);
    Ctrl*     ctrl = (Ctrl*)(ws + OFF_CTRL);
    float*    cand = (float*)(ws + META_BYTES);

    unsigned CAP = 1024u;
    if (ws_size > (size_t)META_BYTES + 4096) CAP = (unsigned)((ws_size - META_BYTES) / 4);
    if (CAP > (16u << 20)) CAP = (16u << 20);   // cap 64 MB of candidates

    hipMemsetAsync(d_ws, 0, META_BYTES, stream);
    k_sample<<<64, 256, 0, stream>>>(p, t, w, hsamp);
    k_scan_sample<<<1, 256, 0, stream>>>(hsamp, ctrl, CAP);
    k_compact<<<2048, 256, 0, stream>>>(p, t, w, cand, ctrl, CAP);
    k_hist1<<<256, 256, 0, stream>>>(cand, ctrl, h1c, h1s, CAP);
    k_scan4096<<<1, 256, 0, stream>>>(h1c, h1s, ctrl, 1);
    k_hist2<<<256, 256, 0, stream>>>(cand, ctrl, h2c, h2s, CAP);
    k_scan4096<<<1, 256, 0, stream>>>(h2c, h2s, ctrl, 2);
    k_hist3<<<256, 256, 0, stream>>>(cand, ctrl, h3c, h3s, CAP);
    k_final<<<1, 256, 0, stream>>>(h3c, h3s, ctrl, (float*)d_out);
}